// Round 1
// baseline (246.292 us; speedup 1.0000x reference)
//
#include <hip/hip_runtime.h>
#include <math.h>

typedef __bf16 bf16;
typedef __bf16 bf16x8 __attribute__((ext_vector_type(8)));
typedef float  f32x4  __attribute__((ext_vector_type(4)));

#define DEV __device__ __forceinline__

DEV void gload_lds16(const bf16* g, bf16* l) {
  __builtin_amdgcn_global_load_lds(
      (const __attribute__((address_space(1))) void*)g,
      (__attribute__((address_space(3))) void*)l, 16, 0, 0);
}

// ---------------- workspace layout (bytes, all 256-aligned) ----------------
// stats:    64 * float2                                   @ 0
// xn:       8192*512 bf16      = 8388608                  @ 512
// wt_qkv:   1536*512 bf16      = 1572864                  @ 8389120
// wot:      512*512 bf16       = 524288                   @ 9961984
// bias_qkv: 1536 f32           = 6144                     @ 10486272
// qkv:      8192*1536 bf16     = 25165824                 @ 10492416
// vt:       2*512*4096 bf16    = 8388608                  @ 35658240
// S:        2*4096*4096 bf16   = 67108864                 @ 44046848
// attn:     8192*512 bf16      = 8388608                  @ 111155712
// total ~119.5 MB
#define OFF_STATS 0UL
#define OFF_XN    512UL
#define OFF_WTQKV 8389120UL
#define OFF_WOT   9961984UL
#define OFF_BIASQ 10486272UL
#define OFF_QKV   10492416UL
#define OFF_VT    35658240UL
#define OFF_S     44046848UL
#define OFF_ATTN  111155712UL

// ---------------- GroupNorm stats: one block per (b,g) ----------------
__global__ __launch_bounds__(256) void gn_stats_k(const float* __restrict__ x,
                                                  float2* __restrict__ stats) {
  const int bg = blockIdx.x;            // 0..63
  const int b = bg >> 5, g = bg & 31;
  const int t = threadIdx.x;
  const float* xp = x + (size_t)b * (4096 * 512) + g * 16 + (t & 3) * 4;
  float s = 0.f, ss = 0.f;
  for (int p = (t >> 2); p < 4096; p += 64) {
    float4 v = *(const float4*)(xp + (size_t)p * 512);
    s  += v.x + v.y + v.z + v.w;
    ss += v.x * v.x + v.y * v.y + v.z * v.z + v.w * v.w;
  }
#pragma unroll
  for (int off = 32; off; off >>= 1) {
    s  += __shfl_xor(s, off);
    ss += __shfl_xor(ss, off);
  }
  __shared__ float rs[4], rss[4];
  const int w = t >> 6, l = t & 63;
  if (l == 0) { rs[w] = s; rss[w] = ss; }
  __syncthreads();
  if (t == 0) {
    float S  = rs[0] + rs[1] + rs[2] + rs[3];
    float SS = rss[0] + rss[1] + rss[2] + rss[3];
    float mean = S * (1.0f / 65536.0f);
    float var  = SS * (1.0f / 65536.0f) - mean * mean;
    stats[bg] = make_float2(mean, 1.0f / sqrtf(var + 1e-6f));
  }
}

// ---------------- normalize + bf16 cast ----------------
__global__ __launch_bounds__(256) void gn_apply_k(const float* __restrict__ x,
                                                  const float2* __restrict__ stats,
                                                  const float* __restrict__ gamma,
                                                  const float* __restrict__ beta,
                                                  bf16* __restrict__ xn) {
  size_t i = ((size_t)blockIdx.x * 256 + threadIdx.x) * 8;
  const int c = (int)(i & 511);
  const int b = (int)(i >> 21);         // 4096*512 = 2^21 per batch
  float2 st = stats[b * 32 + (c >> 4)];
  float4 xa = *(const float4*)(x + i);
  float4 xb = *(const float4*)(x + i + 4);
  float4 ga = *(const float4*)(gamma + c);
  float4 gb = *(const float4*)(gamma + c + 4);
  float4 ba = *(const float4*)(beta + c);
  float4 bb = *(const float4*)(beta + c + 4);
  bf16x8 o;
  o[0] = (bf16)((xa.x - st.x) * st.y * ga.x + ba.x);
  o[1] = (bf16)((xa.y - st.x) * st.y * ga.y + ba.y);
  o[2] = (bf16)((xa.z - st.x) * st.y * ga.z + ba.z);
  o[3] = (bf16)((xa.w - st.x) * st.y * ga.w + ba.w);
  o[4] = (bf16)((xb.x - st.x) * st.y * gb.x + bb.x);
  o[5] = (bf16)((xb.y - st.x) * st.y * gb.y + bb.y);
  o[6] = (bf16)((xb.z - st.x) * st.y * gb.z + bb.z);
  o[7] = (bf16)((xb.w - st.x) * st.y * gb.w + bb.w);
  *(bf16x8*)(xn + i) = o;
}

// ---------------- weight transpose + bf16 convert ----------------
__global__ void prep_w_k(const float* __restrict__ wq, const float* __restrict__ wk,
                         const float* __restrict__ wv, const float* __restrict__ wo,
                         bf16* __restrict__ wt_qkv, bf16* __restrict__ wot, float qscale) {
  const int z = blockIdx.z;
  const float* W = (z == 0) ? wq : (z == 1) ? wk : (z == 2) ? wv : wo;
  bf16* dst = (z < 3) ? (wt_qkv + (size_t)z * 512 * 512) : wot;
  const float s = (z == 0) ? qscale : 1.0f;
  __shared__ float tile[32][33];
  const int i0 = blockIdx.y * 32;       // input-dim
  const int o0 = blockIdx.x * 32;       // output-dim
#pragma unroll
  for (int r = threadIdx.y; r < 32; r += 8)
    tile[r][threadIdx.x] = W[(size_t)(i0 + r) * 512 + o0 + threadIdx.x];
  __syncthreads();
#pragma unroll
  for (int r = threadIdx.y; r < 32; r += 8)
    dst[(size_t)(o0 + r) * 512 + i0 + threadIdx.x] = (bf16)(tile[threadIdx.x][r] * s);
}

__global__ void prep_bias_k(const float* __restrict__ bq, const float* __restrict__ bk,
                            const float* __restrict__ bv, float* __restrict__ bias_qkv,
                            float qscale) {
  int i = blockIdx.x * 256 + threadIdx.x;  // 0..1535
  float v = (i < 512) ? bq[i] * qscale : (i < 1024) ? bk[i - 512] : bv[i - 1024];
  bias_qkv[i] = v;
}

// ---------------- V transpose: qkv[.,1024+d] -> vt[z][d][n] ----------------
__global__ void transpose_v_k(const bf16* __restrict__ qkv, bf16* __restrict__ vt) {
  __shared__ bf16 tile[32][33];
  const int z = blockIdx.z;
  const int n0 = blockIdx.x * 32, d0 = blockIdx.y * 32;
  const bf16* src = qkv + (size_t)z * 4096 * 1536 + 1024;
#pragma unroll
  for (int r = threadIdx.y; r < 32; r += 8)
    tile[r][threadIdx.x] = src[(size_t)(n0 + r) * 1536 + d0 + threadIdx.x];
  __syncthreads();
  bf16* dst = vt + (size_t)z * 512 * 4096;
#pragma unroll
  for (int r = threadIdx.y; r < 32; r += 8)
    dst[(size_t)(d0 + r) * 4096 + n0 + threadIdx.x] = tile[threadIdx.x][r];
}

// ---------------- row softmax over 4096 bf16, in place ----------------
__global__ __launch_bounds__(256) void softmax_k(bf16* __restrict__ S) {
  const int t = threadIdx.x;
  bf16* p = S + (size_t)blockIdx.x * 4096 + t * 16;
  bf16x8 u0 = *(const bf16x8*)p;
  bf16x8 u1 = *(const bf16x8*)(p + 8);
  float v[16];
#pragma unroll
  for (int j = 0; j < 8; ++j) { v[j] = (float)u0[j]; v[j + 8] = (float)u1[j]; }
  float m = v[0];
#pragma unroll
  for (int j = 1; j < 16; ++j) m = fmaxf(m, v[j]);
#pragma unroll
  for (int off = 32; off; off >>= 1) m = fmaxf(m, __shfl_xor(m, off));
  __shared__ float red[4];
  const int w = t >> 6, l = t & 63;
  if (l == 0) red[w] = m;
  __syncthreads();
  m = fmaxf(fmaxf(red[0], red[1]), fmaxf(red[2], red[3]));
  __syncthreads();
  float s = 0.f;
#pragma unroll
  for (int j = 0; j < 16; ++j) { v[j] = __expf(v[j] - m); s += v[j]; }
#pragma unroll
  for (int off = 32; off; off >>= 1) s += __shfl_xor(s, off);
  if (l == 0) red[w] = s;
  __syncthreads();
  s = red[0] + red[1] + red[2] + red[3];
  const float inv = 1.0f / s;
#pragma unroll
  for (int j = 0; j < 8; ++j) { u0[j] = (bf16)(v[j] * inv); u1[j] = (bf16)(v[j + 8] * inv); }
  *(bf16x8*)p = u0;
  *(bf16x8*)(p + 8) = u1;
}

// ---------------- NT bf16 MFMA GEMM (m97 structure) ----------------
// C[M,N] = A[M,K] * B[N,K]^T, both row-major with K contiguous.
// BK=32, 256 threads = 4 waves in 2x2, per-wave (BM/2)x(BN/2) via 16x16x32.
// EPI: 0 = store bf16; 1 = +bias, store bf16; 2 = +bias +resid, store f32.
template <int BM, int BN, int EPI>
__global__ __launch_bounds__(256, 2) void gemm_nt(
    const bf16* __restrict__ A, int lda, long sAz,
    const bf16* __restrict__ B, int ldb, long sBz,
    void* __restrict__ C, int ldc, long sCz,
    int nk,
    const float* __restrict__ bias,
    const float* __restrict__ resid) {
  constexpr int WM = BM / 2, WN = BN / 2;
  constexpr int FM = BM / 32, FN = BN / 32;
  __shared__ alignas(16) bf16 As[2][BM * 32];
  __shared__ alignas(16) bf16 Bs[2][BN * 32];

  const int t = threadIdx.x;
  const int z = blockIdx.z;
  const bf16* Aq = A + (size_t)z * sAz + (size_t)blockIdx.y * BM * lda;
  const bf16* Bq = B + (size_t)z * sBz + (size_t)blockIdx.x * BN * ldb;

  auto stage = [&](int buf, int kt) {
    const int k0 = kt * 32;
#pragma unroll
    for (int i = 0; i < BM / 64; ++i) {
      int r = i * 64 + (t >> 2);
      gload_lds16(Aq + (size_t)r * lda + k0 + (t & 3) * 8, &As[buf][i * 2048 + t * 8]);
    }
#pragma unroll
    for (int i = 0; i < BN / 64; ++i) {
      int r = i * 64 + (t >> 2);
      gload_lds16(Bq + (size_t)r * ldb + k0 + (t & 3) * 8, &Bs[buf][i * 2048 + t * 8]);
    }
  };

  const int l = t & 63, w = t >> 6;
  const int wr = w >> 1, wc = w & 1;
  const int lr = l & 15, kh = l >> 4;

  f32x4 acc[FM][FN] = {};

  stage(0, 0);
  for (int kt = 0; kt < nk; ++kt) {
    __syncthreads();                 // drains vmcnt(0): staged tile ready
    if (kt + 1 < nk) stage((kt + 1) & 1, kt + 1);
    const int buf = kt & 1;
    const bf16* ap = &As[buf][(wr * WM + lr) * 32 + kh * 8];
    const bf16* bp = &Bs[buf][(wc * WN + lr) * 32 + kh * 8];
    bf16x8 a[FM], b[FN];
#pragma unroll
    for (int m = 0; m < FM; ++m) a[m] = *(const bf16x8*)(ap + m * 16 * 32);
#pragma unroll
    for (int n = 0; n < FN; ++n) b[n] = *(const bf16x8*)(bp + n * 16 * 32);
#pragma unroll
    for (int m = 0; m < FM; ++m)
#pragma unroll
      for (int n = 0; n < FN; ++n)
        acc[m][n] = __builtin_amdgcn_mfma_f32_16x16x32_bf16(a[m], b[n], acc[m][n], 0, 0, 0);
  }

  // epilogue: C/D layout col = lane&15, row = (lane>>4)*4 + reg
  const int gr0 = blockIdx.y * BM + wr * WM + kh * 4;
  const int gc0 = blockIdx.x * BN + wc * WN + lr;
#pragma unroll
  for (int m = 0; m < FM; ++m)
#pragma unroll
    for (int n = 0; n < FN; ++n) {
      const int c = gc0 + n * 16;
      float bv = 0.f;
      if constexpr (EPI >= 1) bv = bias[c];
#pragma unroll
      for (int j = 0; j < 4; ++j) {
        const int r = gr0 + m * 16 + j;
        float val = acc[m][n][j] + bv;
        if constexpr (EPI == 2) {
          float* Cf = (float*)C + (size_t)z * sCz;
          Cf[(size_t)r * ldc + c] = val + resid[(size_t)r * ldc + c];
        } else {
          bf16* Cb = (bf16*)C + (size_t)z * sCz;
          Cb[(size_t)r * ldc + c] = (bf16)val;
        }
      }
    }
}

// ---------------- launch ----------------
extern "C" void kernel_launch(void* const* d_in, const int* in_sizes, int n_in,
                              void* d_out, int out_size, void* d_ws, size_t ws_size,
                              hipStream_t stream) {
  const float* x     = (const float*)d_in[0];
  const float* gamma = (const float*)d_in[1];
  const float* beta  = (const float*)d_in[2];
  const float* wq = (const float*)d_in[3];
  const float* bq = (const float*)d_in[4];
  const float* wk = (const float*)d_in[5];
  const float* bk = (const float*)d_in[6];
  const float* wv = (const float*)d_in[7];
  const float* bv = (const float*)d_in[8];
  const float* wo = (const float*)d_in[9];
  const float* bo = (const float*)d_in[10];
  float* out = (float*)d_out;
  char* ws = (char*)d_ws;

  float2* stats    = (float2*)(ws + OFF_STATS);
  bf16*   xn       = (bf16*)(ws + OFF_XN);
  bf16*   wt_qkv   = (bf16*)(ws + OFF_WTQKV);
  bf16*   wot      = (bf16*)(ws + OFF_WOT);
  float*  bias_qkv = (float*)(ws + OFF_BIASQ);
  bf16*   qkv      = (bf16*)(ws + OFF_QKV);
  bf16*   vt       = (bf16*)(ws + OFF_VT);
  bf16*   S        = (bf16*)(ws + OFF_S);
  bf16*   attn     = (bf16*)(ws + OFF_ATTN);

  const float qscale = 0.04419417382415922f;  // 1/sqrt(512)

  prep_w_k<<<dim3(16, 16, 4), dim3(32, 8), 0, stream>>>(wq, wk, wv, wo, wt_qkv, wot, qscale);
  prep_bias_k<<<6, 256, 0, stream>>>(bq, bk, bv, bias_qkv, qscale);
  gn_stats_k<<<64, 256, 0, stream>>>(x, stats);
  gn_apply_k<<<2048, 256, 0, stream>>>(x, stats, gamma, beta, xn);

  // QKV: [8192,512] @ WT[1536,512]^T -> qkv [8192,1536] (+bias, q pre-scaled)
  gemm_nt<128, 128, 1><<<dim3(12, 64, 1), 256, 0, stream>>>(
      xn, 512, 0, wt_qkv, 512, 0, qkv, 1536, 0, 512 / 32, bias_qkv, nullptr);

  // scores: per batch S[4096,4096] = q @ k^T (scale folded into q)
  gemm_nt<128, 128, 0><<<dim3(32, 32, 2), 256, 0, stream>>>(
      qkv, 1536, 4096L * 1536, qkv + 512, 1536, 4096L * 1536,
      S, 4096, 4096L * 4096, 512 / 32, nullptr, nullptr);

  softmax_k<<<8192, 256, 0, stream>>>(S);

  transpose_v_k<<<dim3(128, 16, 2), dim3(32, 8), 0, stream>>>(qkv, vt);

  // attn: per batch [4096,512] = P[4096,4096] @ VT[512,4096]^T
  gemm_nt<128, 64, 0><<<dim3(8, 32, 2), 256, 0, stream>>>(
      S, 4096, 4096L * 4096, vt, 4096, 512L * 4096,
      attn, 512, 4096L * 512, 4096 / 32, nullptr, nullptr);

  // out: [8192,512] = attn @ WOT^T + bo + inputs (fp32)
  gemm_nt<64, 128, 2><<<dim3(4, 128, 1), 256, 0, stream>>>(
      attn, 512, 0, wot, 512, 0, out, 512, 0, 512 / 32, bo, x);
}

// Round 2
// 200.858 us; speedup vs baseline: 1.2262x; 1.2262x over previous
//
#include <hip/hip_runtime.h>
#include <math.h>

typedef __bf16 bf16;
typedef __bf16 bf16x8 __attribute__((ext_vector_type(8)));
typedef float  f32x4  __attribute__((ext_vector_type(4)));

#define DEV __device__ __forceinline__

DEV void gload_lds16(const bf16* g, bf16* l) {
  __builtin_amdgcn_global_load_lds(
      (const __attribute__((address_space(1))) void*)g,
      (__attribute__((address_space(3))) void*)l, 16, 0, 0);
}

// ---------------- workspace layout (bytes) ----------------
#define OFF_STATS 0UL
#define OFF_XN    512UL
#define OFF_WTQKV 8389120UL
#define OFF_WOT   9961984UL
#define OFF_BIASQ 10486272UL
#define OFF_QKV   10492416UL
#define OFF_VT    35658240UL
#define OFF_S     44046848UL
#define OFF_ATTN  111155712UL
// gn partials (1024 float2 = 8KB) live at OFF_S: S is written later by scores GEMM.

// ---------------- GroupNorm partial stats: 1024 blocks ----------------
__global__ __launch_bounds__(256) void gn_part_k(const float* __restrict__ x,
                                                 float2* __restrict__ part) {
  const int blk = blockIdx.x;           // 0..1023
  const int chunk = blk & 15;           // 16 chunks of 256 pixels
  const int bg = blk >> 4;              // 0..63
  const int b = bg >> 5, g = bg & 31;
  const int t = threadIdx.x;
  const int p = chunk * 256 + t;
  const float* xp = x + (size_t)b * (4096 * 512) + (size_t)p * 512 + g * 16;
  float4 v0 = *(const float4*)(xp);
  float4 v1 = *(const float4*)(xp + 4);
  float4 v2 = *(const float4*)(xp + 8);
  float4 v3 = *(const float4*)(xp + 12);
  float s  = v0.x + v0.y + v0.z + v0.w + v1.x + v1.y + v1.z + v1.w
           + v2.x + v2.y + v2.z + v2.w + v3.x + v3.y + v3.z + v3.w;
  float ss = v0.x*v0.x + v0.y*v0.y + v0.z*v0.z + v0.w*v0.w
           + v1.x*v1.x + v1.y*v1.y + v1.z*v1.z + v1.w*v1.w
           + v2.x*v2.x + v2.y*v2.y + v2.z*v2.z + v2.w*v2.w
           + v3.x*v3.x + v3.y*v3.y + v3.z*v3.z + v3.w*v3.w;
#pragma unroll
  for (int off = 32; off; off >>= 1) {
    s  += __shfl_xor(s, off);
    ss += __shfl_xor(ss, off);
  }
  __shared__ float rs[4], rss[4];
  const int w = t >> 6, l = t & 63;
  if (l == 0) { rs[w] = s; rss[w] = ss; }
  __syncthreads();
  if (t == 0)
    part[blk] = make_float2(rs[0] + rs[1] + rs[2] + rs[3],
                            rss[0] + rss[1] + rss[2] + rss[3]);
}

__global__ void gn_finish_k(const float2* __restrict__ part,
                            float2* __restrict__ stats) {
  const int g = threadIdx.x;            // 0..63 (one block of 64)
  float s = 0.f, ss = 0.f;
#pragma unroll
  for (int c = 0; c < 16; ++c) {
    float2 p = part[g * 16 + c];
    s += p.x; ss += p.y;
  }
  float mean = s * (1.0f / 65536.0f);
  float var  = ss * (1.0f / 65536.0f) - mean * mean;
  stats[g] = make_float2(mean, 1.0f / sqrtf(var + 1e-6f));
}

// ---------------- normalize + bf16 cast ----------------
__global__ __launch_bounds__(256) void gn_apply_k(const float* __restrict__ x,
                                                  const float2* __restrict__ stats,
                                                  const float* __restrict__ gamma,
                                                  const float* __restrict__ beta,
                                                  bf16* __restrict__ xn) {
  size_t i = ((size_t)blockIdx.x * 256 + threadIdx.x) * 8;
  const int c = (int)(i & 511);
  const int b = (int)(i >> 21);
  float2 st = stats[b * 32 + (c >> 4)];
  float4 xa = *(const float4*)(x + i);
  float4 xb = *(const float4*)(x + i + 4);
  float4 ga = *(const float4*)(gamma + c);
  float4 gb = *(const float4*)(gamma + c + 4);
  float4 ba = *(const float4*)(beta + c);
  float4 bb = *(const float4*)(beta + c + 4);
  bf16x8 o;
  o[0] = (bf16)((xa.x - st.x) * st.y * ga.x + ba.x);
  o[1] = (bf16)((xa.y - st.x) * st.y * ga.y + ba.y);
  o[2] = (bf16)((xa.z - st.x) * st.y * ga.z + ba.z);
  o[3] = (bf16)((xa.w - st.x) * st.y * ga.w + ba.w);
  o[4] = (bf16)((xb.x - st.x) * st.y * gb.x + bb.x);
  o[5] = (bf16)((xb.y - st.x) * st.y * gb.y + bb.y);
  o[6] = (bf16)((xb.z - st.x) * st.y * gb.z + bb.z);
  o[7] = (bf16)((xb.w - st.x) * st.y * gb.w + bb.w);
  *(bf16x8*)(xn + i) = o;
}

// ---------------- weight transpose + bf16 convert ----------------
__global__ void prep_w_k(const float* __restrict__ wq, const float* __restrict__ wk,
                         const float* __restrict__ wv, const float* __restrict__ wo,
                         bf16* __restrict__ wt_qkv, bf16* __restrict__ wot, float qscale) {
  const int z = blockIdx.z;
  const float* W = (z == 0) ? wq : (z == 1) ? wk : (z == 2) ? wv : wo;
  bf16* dst = (z < 3) ? (wt_qkv + (size_t)z * 512 * 512) : wot;
  const float s = (z == 0) ? qscale : 1.0f;
  __shared__ float tile[32][33];
  const int i0 = blockIdx.y * 32;
  const int o0 = blockIdx.x * 32;
#pragma unroll
  for (int r = threadIdx.y; r < 32; r += 8)
    tile[r][threadIdx.x] = W[(size_t)(i0 + r) * 512 + o0 + threadIdx.x];
  __syncthreads();
#pragma unroll
  for (int r = threadIdx.y; r < 32; r += 8)
    dst[(size_t)(o0 + r) * 512 + i0 + threadIdx.x] = (bf16)(tile[threadIdx.x][r] * s);
}

__global__ void prep_bias_k(const float* __restrict__ bq, const float* __restrict__ bk,
                            const float* __restrict__ bv, float* __restrict__ bias_qkv,
                            float qscale) {
  int i = blockIdx.x * 256 + threadIdx.x;
  float v = (i < 512) ? bq[i] * qscale : (i < 1024) ? bk[i - 512] : bv[i - 1024];
  bias_qkv[i] = v;
}

// ---------------- V transpose ----------------
__global__ void transpose_v_k(const bf16* __restrict__ qkv, bf16* __restrict__ vt) {
  __shared__ bf16 tile[32][33];
  const int z = blockIdx.z;
  const int n0 = blockIdx.x * 32, d0 = blockIdx.y * 32;
  const bf16* src = qkv + (size_t)z * 4096 * 1536 + 1024;
#pragma unroll
  for (int r = threadIdx.y; r < 32; r += 8)
    tile[r][threadIdx.x] = src[(size_t)(n0 + r) * 1536 + d0 + threadIdx.x];
  __syncthreads();
  bf16* dst = vt + (size_t)z * 512 * 4096;
#pragma unroll
  for (int r = threadIdx.y; r < 32; r += 8)
    dst[(size_t)(d0 + r) * 4096 + n0 + threadIdx.x] = tile[threadIdx.x][r];
}

// ---------------- row softmax over 4096 bf16, in place ----------------
__global__ __launch_bounds__(256) void softmax_k(bf16* __restrict__ S) {
  const int t = threadIdx.x;
  bf16* p = S + (size_t)blockIdx.x * 4096 + t * 16;
  bf16x8 u0 = *(const bf16x8*)p;
  bf16x8 u1 = *(const bf16x8*)(p + 8);
  float v[16];
#pragma unroll
  for (int j = 0; j < 8; ++j) { v[j] = (float)u0[j]; v[j + 8] = (float)u1[j]; }
  float m = v[0];
#pragma unroll
  for (int j = 1; j < 16; ++j) m = fmaxf(m, v[j]);
#pragma unroll
  for (int off = 32; off; off >>= 1) m = fmaxf(m, __shfl_xor(m, off));
  __shared__ float red[4];
  const int w = t >> 6, l = t & 63;
  if (l == 0) red[w] = m;
  __syncthreads();
  m = fmaxf(fmaxf(red[0], red[1]), fmaxf(red[2], red[3]));
  __syncthreads();
  float s = 0.f;
#pragma unroll
  for (int j = 0; j < 16; ++j) { v[j] = __expf(v[j] - m); s += v[j]; }
#pragma unroll
  for (int off = 32; off; off >>= 1) s += __shfl_xor(s, off);
  if (l == 0) red[w] = s;
  __syncthreads();
  s = red[0] + red[1] + red[2] + red[3];
  const float inv = 1.0f / s;
#pragma unroll
  for (int j = 0; j < 8; ++j) { u0[j] = (bf16)(v[j] * inv); u1[j] = (bf16)(v[j + 8] * inv); }
  *(bf16x8*)p = u0;
  *(bf16x8*)(p + 8) = u1;
}

// ---------------- NT bf16 MFMA GEMM (m97 structure + XCD-chunked swizzle) ---
// C[M,N] = A[M,K] * B[N,K]^T. Launched as a LINEAR grid of GX*GY*GZ blocks;
// block ids are remapped so each XCD owns a contiguous chunk of the
// (x-fastest) work list -> all x-blocks sharing an A-panel run on one XCD's L2.
template <int BM, int BN, int EPI, int GX, int GY, int GZ>
__global__ __launch_bounds__(256, 2) void gemm_nt(
    const bf16* __restrict__ A, int lda, long sAz,
    const bf16* __restrict__ B, int ldb, long sBz,
    void* __restrict__ C, int ldc, long sCz,
    int nk,
    const float* __restrict__ bias,
    const float* __restrict__ resid) {
  constexpr int WM = BM / 2, WN = BN / 2;
  constexpr int FM = BM / 32, FN = BN / 32;
  constexpr int NWG = GX * GY * GZ;
  constexpr int CPX = NWG / 8;          // all our grids are %8 == 0
  __shared__ alignas(16) bf16 As[2][BM * 32];
  __shared__ alignas(16) bf16 Bs[2][BN * 32];

  const int lin = blockIdx.x;
  const int wid = (lin & 7) * CPX + (lin >> 3);  // bijective XCD-chunked map
  const int bx = wid % GX;
  const int by = (wid / GX) % GY;
  const int bz = wid / (GX * GY);

  const int t = threadIdx.x;
  const bf16* Aq = A + (size_t)bz * sAz + (size_t)by * BM * lda;
  const bf16* Bq = B + (size_t)bz * sBz + (size_t)bx * BN * ldb;

  auto stage = [&](int buf, int kt) {
    const int k0 = kt * 32;
#pragma unroll
    for (int i = 0; i < BM / 64; ++i) {
      int r = i * 64 + (t >> 2);
      gload_lds16(Aq + (size_t)r * lda + k0 + (t & 3) * 8, &As[buf][i * 2048 + t * 8]);
    }
#pragma unroll
    for (int i = 0; i < BN / 64; ++i) {
      int r = i * 64 + (t >> 2);
      gload_lds16(Bq + (size_t)r * ldb + k0 + (t & 3) * 8, &Bs[buf][i * 2048 + t * 8]);
    }
  };

  const int l = t & 63, w = t >> 6;
  const int wr = w >> 1, wc = w & 1;
  const int lr = l & 15, kh = l >> 4;

  f32x4 acc[FM][FN] = {};

  stage(0, 0);
  for (int kt = 0; kt < nk; ++kt) {
    __syncthreads();
    if (kt + 1 < nk) stage((kt + 1) & 1, kt + 1);
    const int buf = kt & 1;
    const bf16* ap = &As[buf][(wr * WM + lr) * 32 + kh * 8];
    const bf16* bp = &Bs[buf][(wc * WN + lr) * 32 + kh * 8];
    bf16x8 a[FM], b[FN];
#pragma unroll
    for (int m = 0; m < FM; ++m) a[m] = *(const bf16x8*)(ap + m * 16 * 32);
#pragma unroll
    for (int n = 0; n < FN; ++n) b[n] = *(const bf16x8*)(bp + n * 16 * 32);
#pragma unroll
    for (int m = 0; m < FM; ++m)
#pragma unroll
      for (int n = 0; n < FN; ++n)
        acc[m][n] = __builtin_amdgcn_mfma_f32_16x16x32_bf16(a[m], b[n], acc[m][n], 0, 0, 0);
  }

  const int gr0 = by * BM + wr * WM + kh * 4;
  const int gc0 = bx * BN + wc * WN + lr;
#pragma unroll
  for (int m = 0; m < FM; ++m)
#pragma unroll
    for (int n = 0; n < FN; ++n) {
      const int c = gc0 + n * 16;
      float bv = 0.f;
      if constexpr (EPI >= 1) bv = bias[c];
#pragma unroll
      for (int j = 0; j < 4; ++j) {
        const int r = gr0 + m * 16 + j;
        float val = acc[m][n][j] + bv;
        if constexpr (EPI == 2) {
          float* Cf = (float*)C + (size_t)bz * sCz;
          Cf[(size_t)r * ldc + c] = val + resid[(size_t)r * ldc + c];
        } else {
          bf16* Cb = (bf16*)C + (size_t)bz * sCz;
          Cb[(size_t)r * ldc + c] = (bf16)val;
        }
      }
    }
}

// ---------------- launch ----------------
extern "C" void kernel_launch(void* const* d_in, const int* in_sizes, int n_in,
                              void* d_out, int out_size, void* d_ws, size_t ws_size,
                              hipStream_t stream) {
  const float* x     = (const float*)d_in[0];
  const float* gamma = (const float*)d_in[1];
  const float* beta  = (const float*)d_in[2];
  const float* wq = (const float*)d_in[3];
  const float* bq = (const float*)d_in[4];
  const float* wk = (const float*)d_in[5];
  const float* bk = (const float*)d_in[6];
  const float* wv = (const float*)d_in[7];
  const float* bv = (const float*)d_in[8];
  const float* wo = (const float*)d_in[9];
  const float* bo = (const float*)d_in[10];
  float* out = (float*)d_out;
  char* ws = (char*)d_ws;

  float2* stats    = (float2*)(ws + OFF_STATS);
  bf16*   xn       = (bf16*)(ws + OFF_XN);
  bf16*   wt_qkv   = (bf16*)(ws + OFF_WTQKV);
  bf16*   wot      = (bf16*)(ws + OFF_WOT);
  float*  bias_qkv = (float*)(ws + OFF_BIASQ);
  bf16*   qkv      = (bf16*)(ws + OFF_QKV);
  bf16*   vt       = (bf16*)(ws + OFF_VT);
  bf16*   S        = (bf16*)(ws + OFF_S);
  bf16*   attn     = (bf16*)(ws + OFF_ATTN);
  float2* gn_part  = (float2*)(ws + OFF_S);   // scratch, dead before S is written

  const float qscale = 0.04419417382415922f;  // 1/sqrt(512)

  prep_w_k<<<dim3(16, 16, 4), dim3(32, 8), 0, stream>>>(wq, wk, wv, wo, wt_qkv, wot, qscale);
  prep_bias_k<<<6, 256, 0, stream>>>(bq, bk, bv, bias_qkv, qscale);
  gn_part_k<<<1024, 256, 0, stream>>>(x, gn_part);
  gn_finish_k<<<1, 64, 0, stream>>>(gn_part, stats);
  gn_apply_k<<<2048, 256, 0, stream>>>(x, stats, gamma, beta, xn);

  // QKV: [8192,512] @ WT[1536,512]^T -> qkv [8192,1536]
  gemm_nt<128, 128, 1, 12, 64, 1><<<768, 256, 0, stream>>>(
      xn, 512, 0, wt_qkv, 512, 0, qkv, 1536, 0, 512 / 32, bias_qkv, nullptr);

  // scores: per batch S[4096,4096] = q @ k^T
  gemm_nt<128, 128, 0, 32, 32, 2><<<2048, 256, 0, stream>>>(
      qkv, 1536, 4096L * 1536, qkv + 512, 1536, 4096L * 1536,
      S, 4096, 4096L * 4096, 512 / 32, nullptr, nullptr);

  softmax_k<<<8192, 256, 0, stream>>>(S);

  transpose_v_k<<<dim3(128, 16, 2), dim3(32, 8), 0, stream>>>(qkv, vt);

  // attn: per batch [4096,512] = P[4096,4096] @ VT[512,4096]^T
  gemm_nt<128, 64, 0, 8, 32, 2><<<512, 256, 0, stream>>>(
      S, 4096, 4096L * 4096, vt, 4096, 512L * 4096,
      attn, 512, 4096L * 512, 4096 / 32, nullptr, nullptr);

  // out: [8192,512] = attn @ WOT^T + bo + inputs (fp32)
  gemm_nt<64, 128, 2, 4, 128, 1><<<512, 256, 0, stream>>>(
      attn, 512, 0, wot, 512, 0, out, 512, 0, 512 / 32, bo, x);
}

// Round 3
// 185.419 us; speedup vs baseline: 1.3283x; 1.0833x over previous
//
#include <hip/hip_runtime.h>
#include <math.h>

typedef __bf16 bf16;
typedef __bf16 bf16x8 __attribute__((ext_vector_type(8)));
typedef float  f32x4  __attribute__((ext_vector_type(4)));

#define DEV __device__ __forceinline__

DEV void gload_lds16(const bf16* g, bf16* l) {
  __builtin_amdgcn_global_load_lds(
      (const __attribute__((address_space(1))) void*)g,
      (__attribute__((address_space(3))) void*)l, 16, 0, 0);
}

// ---------------- workspace layout (bytes) ----------------
#define OFF_STATS 0UL
#define OFF_XN    512UL
#define OFF_WTQKV 8389120UL
#define OFF_WOT   9961984UL
#define OFF_BIASQ 10486272UL
#define OFF_QKV   10492416UL
#define OFF_VT    35658240UL
#define OFF_S     44046848UL
#define OFF_ATTN  111155712UL
// gn partials (1024 float2 = 8KB) live at OFF_S: S is written later by scores GEMM.

// ---------------- GroupNorm partial stats: 1024 blocks ----------------
__global__ __launch_bounds__(256) void gn_part_k(const float* __restrict__ x,
                                                 float2* __restrict__ part) {
  const int blk = blockIdx.x;           // 0..1023
  const int chunk = blk & 15;           // 16 chunks of 256 pixels
  const int bg = blk >> 4;              // 0..63
  const int b = bg >> 5, g = bg & 31;
  const int t = threadIdx.x;
  const int p = chunk * 256 + t;
  const float* xp = x + (size_t)b * (4096 * 512) + (size_t)p * 512 + g * 16;
  float4 v0 = *(const float4*)(xp);
  float4 v1 = *(const float4*)(xp + 4);
  float4 v2 = *(const float4*)(xp + 8);
  float4 v3 = *(const float4*)(xp + 12);
  float s  = v0.x + v0.y + v0.z + v0.w + v1.x + v1.y + v1.z + v1.w
           + v2.x + v2.y + v2.z + v2.w + v3.x + v3.y + v3.z + v3.w;
  float ss = v0.x*v0.x + v0.y*v0.y + v0.z*v0.z + v0.w*v0.w
           + v1.x*v1.x + v1.y*v1.y + v1.z*v1.z + v1.w*v1.w
           + v2.x*v2.x + v2.y*v2.y + v2.z*v2.z + v2.w*v2.w
           + v3.x*v3.x + v3.y*v3.y + v3.z*v3.z + v3.w*v3.w;
#pragma unroll
  for (int off = 32; off; off >>= 1) {
    s  += __shfl_xor(s, off);
    ss += __shfl_xor(ss, off);
  }
  __shared__ float rs[4], rss[4];
  const int w = t >> 6, l = t & 63;
  if (l == 0) { rs[w] = s; rss[w] = ss; }
  __syncthreads();
  if (t == 0)
    part[blk] = make_float2(rs[0] + rs[1] + rs[2] + rs[3],
                            rss[0] + rss[1] + rss[2] + rss[3]);
}

__global__ void gn_finish_k(const float2* __restrict__ part,
                            float2* __restrict__ stats) {
  const int g = threadIdx.x;            // 0..63 (one block of 64)
  float s = 0.f, ss = 0.f;
#pragma unroll
  for (int c = 0; c < 16; ++c) {
    float2 p = part[g * 16 + c];
    s += p.x; ss += p.y;
  }
  float mean = s * (1.0f / 65536.0f);
  float var  = ss * (1.0f / 65536.0f) - mean * mean;
  stats[g] = make_float2(mean, 1.0f / sqrtf(var + 1e-6f));
}

// ---------------- normalize + bf16 cast ----------------
__global__ __launch_bounds__(256) void gn_apply_k(const float* __restrict__ x,
                                                  const float2* __restrict__ stats,
                                                  const float* __restrict__ gamma,
                                                  const float* __restrict__ beta,
                                                  bf16* __restrict__ xn) {
  size_t i = ((size_t)blockIdx.x * 256 + threadIdx.x) * 8;
  const int c = (int)(i & 511);
  const int b = (int)(i >> 21);
  float2 st = stats[b * 32 + (c >> 4)];
  float4 xa = *(const float4*)(x + i);
  float4 xb = *(const float4*)(x + i + 4);
  float4 ga = *(const float4*)(gamma + c);
  float4 gb = *(const float4*)(gamma + c + 4);
  float4 ba = *(const float4*)(beta + c);
  float4 bb = *(const float4*)(beta + c + 4);
  bf16x8 o;
  o[0] = (bf16)((xa.x - st.x) * st.y * ga.x + ba.x);
  o[1] = (bf16)((xa.y - st.x) * st.y * ga.y + ba.y);
  o[2] = (bf16)((xa.z - st.x) * st.y * ga.z + ba.z);
  o[3] = (bf16)((xa.w - st.x) * st.y * ga.w + ba.w);
  o[4] = (bf16)((xb.x - st.x) * st.y * gb.x + bb.x);
  o[5] = (bf16)((xb.y - st.x) * st.y * gb.y + bb.y);
  o[6] = (bf16)((xb.z - st.x) * st.y * gb.z + bb.z);
  o[7] = (bf16)((xb.w - st.x) * st.y * gb.w + bb.w);
  *(bf16x8*)(xn + i) = o;
}

// ---------------- weight transpose + bf16 convert ----------------
__global__ void prep_w_k(const float* __restrict__ wq, const float* __restrict__ wk,
                         const float* __restrict__ wv, const float* __restrict__ wo,
                         bf16* __restrict__ wt_qkv, bf16* __restrict__ wot, float qscale) {
  const int z = blockIdx.z;
  const float* W = (z == 0) ? wq : (z == 1) ? wk : (z == 2) ? wv : wo;
  bf16* dst = (z < 3) ? (wt_qkv + (size_t)z * 512 * 512) : wot;
  const float s = (z == 0) ? qscale : 1.0f;
  __shared__ float tile[32][33];
  const int i0 = blockIdx.y * 32;
  const int o0 = blockIdx.x * 32;
#pragma unroll
  for (int r = threadIdx.y; r < 32; r += 8)
    tile[r][threadIdx.x] = W[(size_t)(i0 + r) * 512 + o0 + threadIdx.x];
  __syncthreads();
#pragma unroll
  for (int r = threadIdx.y; r < 32; r += 8)
    dst[(size_t)(o0 + r) * 512 + i0 + threadIdx.x] = (bf16)(tile[threadIdx.x][r] * s);
}

__global__ void prep_bias_k(const float* __restrict__ bq, const float* __restrict__ bk,
                            const float* __restrict__ bv, float* __restrict__ bias_qkv,
                            float qscale) {
  int i = blockIdx.x * 256 + threadIdx.x;
  float v = (i < 512) ? bq[i] * qscale : (i < 1024) ? bk[i - 512] : bv[i - 1024];
  bias_qkv[i] = v;
}

// ---------------- V transpose ----------------
__global__ void transpose_v_k(const bf16* __restrict__ qkv, bf16* __restrict__ vt) {
  __shared__ bf16 tile[32][33];
  const int z = blockIdx.z;
  const int n0 = blockIdx.x * 32, d0 = blockIdx.y * 32;
  const bf16* src = qkv + (size_t)z * 4096 * 1536 + 1024;
#pragma unroll
  for (int r = threadIdx.y; r < 32; r += 8)
    tile[r][threadIdx.x] = src[(size_t)(n0 + r) * 1536 + d0 + threadIdx.x];
  __syncthreads();
  bf16* dst = vt + (size_t)z * 512 * 4096;
#pragma unroll
  for (int r = threadIdx.y; r < 32; r += 8)
    dst[(size_t)(d0 + r) * 4096 + n0 + threadIdx.x] = tile[threadIdx.x][r];
}

// ---------------- row softmax over 4096 bf16, in place ----------------
__global__ __launch_bounds__(256) void softmax_k(bf16* __restrict__ S) {
  const int t = threadIdx.x;
  bf16* p = S + (size_t)blockIdx.x * 4096 + t * 16;
  bf16x8 u0 = *(const bf16x8*)p;
  bf16x8 u1 = *(const bf16x8*)(p + 8);
  float v[16];
#pragma unroll
  for (int j = 0; j < 8; ++j) { v[j] = (float)u0[j]; v[j + 8] = (float)u1[j]; }
  float m = v[0];
#pragma unroll
  for (int j = 1; j < 16; ++j) m = fmaxf(m, v[j]);
#pragma unroll
  for (int off = 32; off; off >>= 1) m = fmaxf(m, __shfl_xor(m, off));
  __shared__ float red[4];
  const int w = t >> 6, l = t & 63;
  if (l == 0) red[w] = m;
  __syncthreads();
  m = fmaxf(fmaxf(red[0], red[1]), fmaxf(red[2], red[3]));
  __syncthreads();
  float s = 0.f;
#pragma unroll
  for (int j = 0; j < 16; ++j) { v[j] = __expf(v[j] - m); s += v[j]; }
#pragma unroll
  for (int off = 32; off; off >>= 1) s += __shfl_xor(s, off);
  if (l == 0) red[w] = s;
  __syncthreads();
  s = red[0] + red[1] + red[2] + red[3];
  const float inv = 1.0f / s;
#pragma unroll
  for (int j = 0; j < 8; ++j) { u0[j] = (bf16)(v[j] * inv); u1[j] = (bf16)(v[j + 8] * inv); }
  *(bf16x8*)p = u0;
  *(bf16x8*)(p + 8) = u1;
}

// ---------------- NT bf16 MFMA GEMM: BK=64, XOR-swizzled LDS ----------------
// C[M,N] = A[M,K] * B[N,K]^T, K-contiguous operands.
// LDS tile [R][64] bf16 (128B rows): every row starts at bank 0, so the
// 16B-granule index alone determines the bank. Swizzle: granule ^= (row&7),
// applied on the global SOURCE address at stage time (LDS dest stays linear,
// as global_load_lds requires) and on the ds_read address (same involution).
// Grid is linear; block ids remapped so each XCD owns a contiguous chunk.
template <int BM, int BN, int EPI, int GX, int GY, int GZ>
__global__ __launch_bounds__(256, 2) void gemm_nt(
    const bf16* __restrict__ A, int lda, long sAz,
    const bf16* __restrict__ B, int ldb, long sBz,
    void* __restrict__ C, int ldc, long sCz,
    int nk,
    const float* __restrict__ bias,
    const float* __restrict__ resid) {
  constexpr int WM = BM / 2, WN = BN / 2;
  constexpr int FM = BM / 32, FN = BN / 32;
  constexpr int NWG = GX * GY * GZ;
  constexpr int CPX = NWG / 8;
  __shared__ alignas(16) bf16 As[2][BM * 64];
  __shared__ alignas(16) bf16 Bs[2][BN * 64];

  const int lin = blockIdx.x;
  const int wid = (lin & 7) * CPX + (lin >> 3);  // bijective XCD-chunked map
  const int bx = wid % GX;
  const int by = (wid / GX) % GY;
  const int bz = wid / (GX * GY);

  const int t = threadIdx.x;
  const bf16* Aq = A + (size_t)bz * sAz + (size_t)by * BM * lda;
  const bf16* Bq = B + (size_t)bz * sBz + (size_t)bx * BN * ldb;

  const int srow = t >> 3;                    // 0..31 (row within 32-row pass)
  const int sg   = (t & 7) ^ (srow & 7);      // pre-swizzled source granule
  // LDS dest offset t*8 elems == row*64 + (t&7)*8: linear in lane, as required.

  auto stage = [&](int buf, int kt) {
    const int k0 = kt * 64 + sg * 8;
#pragma unroll
    for (int i = 0; i < BM / 32; ++i)
      gload_lds16(Aq + (size_t)(i * 32 + srow) * lda + k0, &As[buf][i * 2048 + t * 8]);
#pragma unroll
    for (int i = 0; i < BN / 32; ++i)
      gload_lds16(Bq + (size_t)(i * 32 + srow) * ldb + k0, &Bs[buf][i * 2048 + t * 8]);
  };

  const int l = t & 63, w = t >> 6;
  const int wr = w >> 1, wc = w & 1;
  const int lr = l & 15, kh = l >> 4;
  const int rs = lr & 7;                      // (fragment row)&7 for all m,n

  f32x4 acc[FM][FN] = {};

  stage(0, 0);
  for (int kt = 0; kt < nk; ++kt) {
    __syncthreads();                          // staged tile ready (vmcnt drained)
    if (kt + 1 < nk) stage((kt + 1) & 1, kt + 1);
    const int buf = kt & 1;
    bf16x8 a[2][FM], b[2][FN];
#pragma unroll
    for (int h = 0; h < 2; ++h) {
      const int g = ((h * 4 + kh) ^ rs) * 8;  // swizzled granule for this k-half
#pragma unroll
      for (int m = 0; m < FM; ++m)
        a[h][m] = *(const bf16x8*)(&As[buf][(wr * WM + m * 16 + lr) * 64 + g]);
#pragma unroll
      for (int n = 0; n < FN; ++n)
        b[h][n] = *(const bf16x8*)(&Bs[buf][(wc * WN + n * 16 + lr) * 64 + g]);
    }
#pragma unroll
    for (int h = 0; h < 2; ++h)
#pragma unroll
      for (int m = 0; m < FM; ++m)
#pragma unroll
        for (int n = 0; n < FN; ++n)
          acc[m][n] = __builtin_amdgcn_mfma_f32_16x16x32_bf16(a[h][m], b[h][n], acc[m][n], 0, 0, 0);
  }

  // epilogue: C/D layout col = lane&15, row = (lane>>4)*4 + reg
  const int gr0 = by * BM + wr * WM + kh * 4;
  const int gc0 = bx * BN + wc * WN + lr;
#pragma unroll
  for (int m = 0; m < FM; ++m)
#pragma unroll
    for (int n = 0; n < FN; ++n) {
      const int c = gc0 + n * 16;
      float bv = 0.f;
      if constexpr (EPI >= 1) bv = bias[c];
#pragma unroll
      for (int j = 0; j < 4; ++j) {
        const int r = gr0 + m * 16 + j;
        float val = acc[m][n][j] + bv;
        if constexpr (EPI == 2) {
          float* Cf = (float*)C + (size_t)bz * sCz;
          Cf[(size_t)r * ldc + c] = val + resid[(size_t)r * ldc + c];
        } else {
          bf16* Cb = (bf16*)C + (size_t)bz * sCz;
          Cb[(size_t)r * ldc + c] = (bf16)val;
        }
      }
    }
}

// ---------------- launch ----------------
extern "C" void kernel_launch(void* const* d_in, const int* in_sizes, int n_in,
                              void* d_out, int out_size, void* d_ws, size_t ws_size,
                              hipStream_t stream) {
  const float* x     = (const float*)d_in[0];
  const float* gamma = (const float*)d_in[1];
  const float* beta  = (const float*)d_in[2];
  const float* wq = (const float*)d_in[3];
  const float* bq = (const float*)d_in[4];
  const float* wk = (const float*)d_in[5];
  const float* bk = (const float*)d_in[6];
  const float* wv = (const float*)d_in[7];
  const float* bv = (const float*)d_in[8];
  const float* wo = (const float*)d_in[9];
  const float* bo = (const float*)d_in[10];
  float* out = (float*)d_out;
  char* ws = (char*)d_ws;

  float2* stats    = (float2*)(ws + OFF_STATS);
  bf16*   xn       = (bf16*)(ws + OFF_XN);
  bf16*   wt_qkv   = (bf16*)(ws + OFF_WTQKV);
  bf16*   wot      = (bf16*)(ws + OFF_WOT);
  float*  bias_qkv = (float*)(ws + OFF_BIASQ);
  bf16*   qkv      = (bf16*)(ws + OFF_QKV);
  bf16*   vt       = (bf16*)(ws + OFF_VT);
  bf16*   S        = (bf16*)(ws + OFF_S);
  bf16*   attn     = (bf16*)(ws + OFF_ATTN);
  float2* gn_part  = (float2*)(ws + OFF_S);   // scratch, dead before S is written

  const float qscale = 0.04419417382415922f;  // 1/sqrt(512)

  prep_w_k<<<dim3(16, 16, 4), dim3(32, 8), 0, stream>>>(wq, wk, wv, wo, wt_qkv, wot, qscale);
  prep_bias_k<<<6, 256, 0, stream>>>(bq, bk, bv, bias_qkv, qscale);
  gn_part_k<<<1024, 256, 0, stream>>>(x, gn_part);
  gn_finish_k<<<1, 64, 0, stream>>>(gn_part, stats);
  gn_apply_k<<<2048, 256, 0, stream>>>(x, stats, gamma, beta, xn);

  // QKV: [8192,512] @ WT[1536,512]^T -> qkv [8192,1536]
  gemm_nt<128, 128, 1, 12, 64, 1><<<768, 256, 0, stream>>>(
      xn, 512, 0, wt_qkv, 512, 0, qkv, 1536, 0, 512 / 64, bias_qkv, nullptr);

  // scores: per batch S[4096,4096] = q @ k^T
  gemm_nt<128, 128, 0, 32, 32, 2><<<2048, 256, 0, stream>>>(
      qkv, 1536, 4096L * 1536, qkv + 512, 1536, 4096L * 1536,
      S, 4096, 4096L * 4096, 512 / 64, nullptr, nullptr);

  softmax_k<<<8192, 256, 0, stream>>>(S);

  transpose_v_k<<<dim3(128, 16, 2), dim3(32, 8), 0, stream>>>(qkv, vt);

  // attn: per batch [4096,512] = P[4096,4096] @ VT[512,4096]^T
  gemm_nt<128, 64, 0, 8, 32, 2><<<512, 256, 0, stream>>>(
      S, 4096, 4096L * 4096, vt, 4096, 512L * 4096,
      attn, 512, 4096L * 512, 4096 / 64, nullptr, nullptr);

  // out: [8192,512] = attn @ WOT^T + bo + inputs (fp32)
  gemm_nt<64, 128, 2, 4, 128, 1><<<512, 256, 0, stream>>>(
      attn, 512, 0, wot, 512, 0, out, 512, 0, 512 / 64, bo, x);
}